// Round 1
// baseline (1296.791 us; speedup 1.0000x reference)
//
#include <hip/hip_runtime.h>
#include <hip/hip_bf16.h>

#define RRELU_SLOPE (11.0f / 48.0f)

// ---------------------------------------------------------------------------
// Sizes (compile-time constants for this problem)
//   B=32 subjects, N=264 nets, D=375 feat dim, P=N*(N-1)/2=34716 pairs
// ---------------------------------------------------------------------------
#define NB 32
#define NN 264
#define ND 375
#define NP 34716

// ---------------------------------------------------------------------------
// Kernel 1: feature extractor + u/v precompute.
// One wave (64 lanes) per row r = b*N + n.  Outputs in INTERLEAVED layout so
// sim_kernel reads are lane-coalesced:
//   U[((n*8 + q)*32 + b)*4 + c] = (feats(b,n) @ sm_w1[0:32,:] + sm_b1)[q*4+c]
//   V[((n*8 + q)*32 + b)*4 + c] = (feats(b,n) @ sm_w1[32:64,:])[q*4+c]
// ---------------------------------------------------------------------------
__global__ __launch_bounds__(256) void fe_uv_kernel(
    const float* __restrict__ x,
    const float* __restrict__ w1, const float* __restrict__ b1,
    const float* __restrict__ w2, const float* __restrict__ b2,
    const float* __restrict__ w3, const float* __restrict__ b3,
    const float* __restrict__ smw1, const float* __restrict__ smb1,
    float* __restrict__ U, float* __restrict__ V)
{
    __shared__ float h[4][64];
    const int lane = threadIdx.x & 63;
    const int wave = threadIdx.x >> 6;
    const int row  = blockIdx.x * 4 + wave;          // exactly 8448 rows
    const int urow = __builtin_amdgcn_readfirstlane(row);  // wave-uniform -> s_loads for x
    const float* xr = x + (size_t)urow * ND;

    // layer 1: 375 -> 64, rrelu
    float a1 = b1[lane];
#pragma unroll 5
    for (int d = 0; d < ND; ++d)
        a1 = fmaf(xr[d], w1[d * 64 + lane], a1);
    a1 = (a1 >= 0.f) ? a1 : a1 * RRELU_SLOPE;
    h[wave][lane] = a1;
    __syncthreads();

    // layer 2: 64 -> 64, relu
    float a2 = b2[lane];
#pragma unroll 8
    for (int c = 0; c < 64; ++c)
        a2 = fmaf(h[wave][c], w2[c * 64 + lane], a2);
    a2 = fmaxf(a2, 0.f);
    __syncthreads();
    h[wave][lane] = a2;
    __syncthreads();

    // layer 3: 64 -> 32 (no act).  Both half-waves compute the same feats.
    const int o = lane & 31;
    float f = b3[o];
#pragma unroll 8
    for (int c = 0; c < 64; ++c)
        f = fmaf(h[wave][c], w3[c * 32 + o], f);
    __syncthreads();
    if (lane < 32) h[wave][lane] = f;
    __syncthreads();

    // u (lanes 0..31) / v (lanes 32..63): feats @ sm_w1 halves
    const float* sw = smw1 + ((lane < 32) ? 0 : 32 * 32);
    float uv = (lane < 32) ? smb1[o] : 0.f;
#pragma unroll 8
    for (int c = 0; c < 32; ++c)
        uv = fmaf(h[wave][c], sw[c * 32 + o], uv);

    const int bb = urow / NN;
    const int nn = urow - bb * NN;
    // interleaved store: feature o -> (q = o>>2, c = o&3)
    float* dst = ((lane < 32) ? U : V)
               + (((size_t)nn * 8 + (o >> 2)) * 32 + bb) * 4 + (o & 3);
    *dst = uv;
}

// ---------------------------------------------------------------------------
// Kernel 2: similarity MLP over all pairs.  Thread = (b, p); 8 pairs/block.
// U/V reads are now fully coalesced: lane b reads float4 at [(i*8+q)*32+b].
// Writes sT[p*32 + b] = tanh(...) (s transposed for the big GEMM).
// ---------------------------------------------------------------------------
__device__ __forceinline__ int cfun(int i) {           // pairs before row i
    return i * NN - (i * (i + 1)) / 2;
}

__global__ __launch_bounds__(256, 1) void sim_kernel(
    const float* __restrict__ U, const float* __restrict__ V,
    const float* __restrict__ w2, const float* __restrict__ b2,
    const float* __restrict__ w3, const float* __restrict__ b3,
    const float* __restrict__ w4, const float* __restrict__ b4,
    float* __restrict__ sT)
{
    const int t = threadIdx.x;
    const int b = t & 31;
    const int p = blockIdx.x * 8 + (t >> 5);
    if (p >= NP) return;

    // invert triangular index: largest i with cfun(i) <= p
    int i = (int)((527.0f - sqrtf(277729.0f - 8.0f * (float)p)) * 0.5f);
    i = max(0, min(NN - 2, i));
    while (i < NN - 2 && cfun(i + 1) <= p) ++i;
    while (i > 0 && cfun(i) > p) --i;
    const int j = i + 1 + (p - cfun(i));

    const float4* u4 = (const float4*)U + (size_t)i * 256 + b;   // +q*32 steps
    const float4* v4 = (const float4*)V + (size_t)j * 256 + b;

    float h2[16];
#pragma unroll
    for (int o = 0; o < 16; ++o) h2[o] = b2[o];

#pragma unroll
    for (int q = 0; q < 8; ++q) {
        float4 uu = u4[q * 32], vv = v4[q * 32];
        float h1c[4];
        h1c[0] = fmaxf(uu.x + vv.x, 0.f);
        h1c[1] = fmaxf(uu.y + vv.y, 0.f);
        h1c[2] = fmaxf(uu.z + vv.z, 0.f);
        h1c[3] = fmaxf(uu.w + vv.w, 0.f);
#pragma unroll
        for (int c = 0; c < 4; ++c)
#pragma unroll
            for (int o = 0; o < 16; ++o)
                h2[o] = fmaf(h1c[c], w2[(q * 4 + c) * 16 + o], h2[o]);
    }
#pragma unroll
    for (int o = 0; o < 16; ++o) h2[o] = fmaxf(h2[o], 0.f);

    float h3[8];
#pragma unroll
    for (int o = 0; o < 8; ++o) h3[o] = b3[o];
#pragma unroll
    for (int c = 0; c < 16; ++c)
#pragma unroll
        for (int o = 0; o < 8; ++o)
            h3[o] = fmaf(h2[c], w3[c * 8 + o], h3[o]);
#pragma unroll
    for (int o = 0; o < 8; ++o) h3[o] = fmaxf(h3[o], 0.f);

    float z = b4[0];
#pragma unroll
    for (int c = 0; c < 8; ++c) z = fmaf(h3[c], w4[c], z);

    sT[(size_t)p * 32 + b] = tanhf(z);
}

// ---------------------------------------------------------------------------
// Kernel 3: split-K GEMM  C[m,n] = sum_k aT[k,m] * w[k,n]   (m = 0..31)
// aT K-tiles staged through LDS so the inner loop's VMEM queue carries ONLY
// the coalesced HBM stream of w (no broadcast float4 loads stuck behind
// HBM misses in the in-order vmcnt queue).  LDS reads are same-address
// broadcast ds_read_b128 -> conflict-free.
// ---------------------------------------------------------------------------
__global__ __launch_bounds__(256, 1) void gemm_splitk(
    const float* __restrict__ aT, const float* __restrict__ w,
    float* __restrict__ partial, int K, int N, int chunk)
{
    __shared__ float sa[256 * 32];                    // 32 KB K-tile of aT
    const int n  = blockIdx.x * 256 + threadIdx.x;
    const int ns = blockIdx.y;
    const int k0 = ns * chunk;
    const int k1 = min(k0 + chunk, K);

    float acc[32];
#pragma unroll
    for (int m = 0; m < 32; ++m) acc[m] = 0.f;

    const float* wp = w + (size_t)k0 * N + n;
    for (int kt = k0; kt < k1; kt += 256) {
        const int klen = min(256, k1 - kt);
        __syncthreads();
        // stage aT[kt .. kt+klen) x 32 into LDS, coalesced float4
        const float4* src  = (const float4*)(aT + (size_t)kt * 32);
        float4*       dstl = (float4*)sa;
        for (int idx = threadIdx.x; idx < klen * 8; idx += 256)
            dstl[idx] = src[idx];
        __syncthreads();

#pragma unroll 8
        for (int k = 0; k < klen; ++k) {
            const float wv = *wp; wp += N;            // pure HBM stream
            const float4* a4 = (const float4*)(sa + k * 32);
#pragma unroll
            for (int mq = 0; mq < 8; ++mq) {
                float4 av = a4[mq];
                acc[mq * 4 + 0] = fmaf(av.x, wv, acc[mq * 4 + 0]);
                acc[mq * 4 + 1] = fmaf(av.y, wv, acc[mq * 4 + 1]);
                acc[mq * 4 + 2] = fmaf(av.z, wv, acc[mq * 4 + 2]);
                acc[mq * 4 + 3] = fmaf(av.w, wv, acc[mq * 4 + 3]);
            }
        }
    }

    float* po = partial + ((size_t)ns * N + n) * 32;
#pragma unroll
    for (int m = 0; m < 32; ++m) po[m] = acc[m];
}

// ---------------------------------------------------------------------------
// Kernel 4/6: reduce split-K partials + bias + activation.
// out[n*32+b] layout == aT layout for the next GEMM.  mode 0=rrelu, 1=relu
// ---------------------------------------------------------------------------
__global__ __launch_bounds__(256) void reduce_act(
    const float* __restrict__ partial, const float* __restrict__ bias,
    float* __restrict__ out, int NT, int ns_count, int mode)
{
    const int idx = blockIdx.x * 256 + threadIdx.x;   // < NT = N*32
    const int n = idx >> 5;
    float s = bias[n];
#pragma unroll 4
    for (int ns = 0; ns < ns_count; ++ns)
        s += partial[(size_t)ns * NT + idx];
    out[idx] = (mode == 0) ? ((s >= 0.f) ? s : s * RRELU_SLOPE) : fmaxf(s, 0.f);
}

// ---------------------------------------------------------------------------
// Kernel 7: layer3 (256 -> 64, relu).  8 blocks; thread = (b, o).
// c3T[o*32+b]
// ---------------------------------------------------------------------------
__global__ __launch_bounds__(256) void layer3_kernel(
    const float* __restrict__ c2T, const float* __restrict__ w3,
    const float* __restrict__ b3, float* __restrict__ c3T)
{
    const int t = threadIdx.x;
    const int b = t & 31;
    const int o = blockIdx.x * 8 + (t >> 5);
    float acc = b3[o];
#pragma unroll 8
    for (int k = 0; k < 256; ++k)
        acc = fmaf(c2T[k * 32 + b], w3[k * 64 + o], acc);
    c3T[o * 32 + b] = fmaxf(acc, 0.f);
}

// ---------------------------------------------------------------------------
// Kernel 8: layer4 (64 -> 3) + log_softmax.  Single small block.
// ---------------------------------------------------------------------------
__global__ __launch_bounds__(128) void final_kernel(
    const float* __restrict__ c3T, const float* __restrict__ w4,
    const float* __restrict__ b4, float* __restrict__ out)
{
    __shared__ float c4s[96];
    __shared__ float lse[32];
    const int t = threadIdx.x;
    if (t < 96) {
        const int b = t / 3, j = t - b * 3;
        float acc = b4[j];
#pragma unroll
        for (int c = 0; c < 64; ++c)
            acc = fmaf(c3T[c * 32 + b], w4[c * 3 + j], acc);
        c4s[t] = acc;
    }
    __syncthreads();
    if (t < 32) {
        const float a0 = c4s[t * 3], a1 = c4s[t * 3 + 1], a2 = c4s[t * 3 + 2];
        const float m = fmaxf(a0, fmaxf(a1, a2));
        lse[t] = m + logf(expf(a0 - m) + expf(a1 - m) + expf(a2 - m));
    }
    __syncthreads();
    if (t < 96) out[t] = c4s[t] - lse[t / 3];
}

// ---------------------------------------------------------------------------
extern "C" void kernel_launch(void* const* d_in, const int* in_sizes, int n_in,
                              void* d_out, int out_size, void* d_ws, size_t ws_size,
                              hipStream_t stream)
{
    const float* x     = (const float*)d_in[0];
    const float* fe_w1 = (const float*)d_in[1];
    const float* fe_b1 = (const float*)d_in[2];
    const float* fe_w2 = (const float*)d_in[3];
    const float* fe_b2 = (const float*)d_in[4];
    const float* fe_w3 = (const float*)d_in[5];
    const float* fe_b3 = (const float*)d_in[6];
    const float* sm_w1 = (const float*)d_in[7];
    const float* sm_b1 = (const float*)d_in[8];
    const float* sm_w2 = (const float*)d_in[9];
    const float* sm_b2 = (const float*)d_in[10];
    const float* sm_w3 = (const float*)d_in[11];
    const float* sm_b3 = (const float*)d_in[12];
    const float* sm_w4 = (const float*)d_in[13];
    const float* sm_b4 = (const float*)d_in[14];
    const float* cl_w1 = (const float*)d_in[15];
    const float* cl_b1 = (const float*)d_in[16];
    const float* cl_w2 = (const float*)d_in[17];
    const float* cl_b2 = (const float*)d_in[18];
    const float* cl_w3 = (const float*)d_in[19];
    const float* cl_b3 = (const float*)d_in[20];
    const float* cl_w4 = (const float*)d_in[21];
    const float* cl_b4 = (const float*)d_in[22];

    float* ws  = (float*)d_ws;
    float* U   = ws;                    // 264*8*32*4      = 270336
    float* V   = U   + 270336;          // 270336
    float* sT  = V   + 270336;          // 34716*32        = 1110912
    float* p1  = sT  + 1110912;         // 32*4096*32      = 4194304
    float* c1T = p1  + 4194304;         // 4096*32         = 131072
    float* p2  = c1T + 131072;          // 128*256*32      = 1048576
    float* c2T = p2  + 1048576;         // 256*32          = 8192
    float* c3T = c2T + 8192;            // 64*32           = 2048
    // total: 7,035,776 floats = 28.1 MB

    // 1) feature extractor + u/v  (8448 rows, 4 waves/block)
    hipLaunchKernelGGL(fe_uv_kernel, dim3(2112), dim3(256), 0, stream,
                       x, fe_w1, fe_b1, fe_w2, fe_b2, fe_w3, fe_b3,
                       sm_w1, sm_b1, U, V);
    // 2) pair similarity MLP -> sT[p][b]
    hipLaunchKernelGGL(sim_kernel, dim3((NP + 7) / 8), dim3(256), 0, stream,
                       U, V, sm_w2, sm_b2, sm_w3, sm_b3, sm_w4, sm_b4, sT);
    // 3) big GEMM: s[32,P] @ cl_w1[P,4096]  (split-K 32, LDS-staged aT)
    hipLaunchKernelGGL(gemm_splitk, dim3(16, 32), dim3(256), 0, stream,
                       sT, cl_w1, p1, NP, 4096, 1085);
    // 4) reduce + bias + rrelu -> c1T[4096][32]
    hipLaunchKernelGGL(reduce_act, dim3(512), dim3(256), 0, stream,
                       p1, cl_b1, c1T, 4096 * 32, 32, 0);
    // 5) layer2 GEMM: c1[32,4096] @ cl_w2[4096,256]  (split-K 128)
    hipLaunchKernelGGL(gemm_splitk, dim3(1, 128), dim3(256), 0, stream,
                       c1T, cl_w2, p2, 4096, 256, 32);
    // 6) reduce + bias + relu -> c2T[256][32]
    hipLaunchKernelGGL(reduce_act, dim3(32), dim3(256), 0, stream,
                       p2, cl_b2, c2T, 256 * 32, 128, 1);
    // 7) layer3: 256 -> 64, relu -> c3T[64][32]
    hipLaunchKernelGGL(layer3_kernel, dim3(8), dim3(256), 0, stream,
                       c2T, cl_w3, cl_b3, c3T);
    // 8) layer4 + log_softmax -> out[32,3]
    hipLaunchKernelGGL(final_kernel, dim3(1), dim3(128), 0, stream,
                       c3T, cl_w4, cl_b4, (float*)d_out);
}

// Round 2
// 907.523 us; speedup vs baseline: 1.4289x; 1.4289x over previous
//
#include <hip/hip_runtime.h>
#include <hip/hip_bf16.h>

#define RRELU_SLOPE (11.0f / 48.0f)

// ---------------------------------------------------------------------------
// Sizes (compile-time constants for this problem)
//   B=32 subjects, N=264 nets, D=375 feat dim, P=N*(N-1)/2=34716 pairs
// ---------------------------------------------------------------------------
#define NB 32
#define NN 264
#define ND 375
#define NP 34716

// ---------------------------------------------------------------------------
// Kernel 1: feature extractor + u/v precompute.
// One wave (64 lanes) per row r = b*N + n.  Outputs in INTERLEAVED layout so
// sim_kernel reads are lane-coalesced:
//   U[((n*8 + q)*32 + b)*4 + c] = (feats(b,n) @ sm_w1[0:32,:] + sm_b1)[q*4+c]
//   V[((n*8 + q)*32 + b)*4 + c] = (feats(b,n) @ sm_w1[32:64,:])[q*4+c]
// ---------------------------------------------------------------------------
__global__ __launch_bounds__(256) void fe_uv_kernel(
    const float* __restrict__ x,
    const float* __restrict__ w1, const float* __restrict__ b1,
    const float* __restrict__ w2, const float* __restrict__ b2,
    const float* __restrict__ w3, const float* __restrict__ b3,
    const float* __restrict__ smw1, const float* __restrict__ smb1,
    float* __restrict__ U, float* __restrict__ V)
{
    __shared__ float h[4][64];
    const int lane = threadIdx.x & 63;
    const int wave = threadIdx.x >> 6;
    const int row  = blockIdx.x * 4 + wave;          // exactly 8448 rows
    const int urow = __builtin_amdgcn_readfirstlane(row);  // wave-uniform -> s_loads for x
    const float* xr = x + (size_t)urow * ND;

    // layer 1: 375 -> 64, rrelu
    float a1 = b1[lane];
#pragma unroll 5
    for (int d = 0; d < ND; ++d)
        a1 = fmaf(xr[d], w1[d * 64 + lane], a1);
    a1 = (a1 >= 0.f) ? a1 : a1 * RRELU_SLOPE;
    h[wave][lane] = a1;
    __syncthreads();

    // layer 2: 64 -> 64, relu
    float a2 = b2[lane];
#pragma unroll 8
    for (int c = 0; c < 64; ++c)
        a2 = fmaf(h[wave][c], w2[c * 64 + lane], a2);
    a2 = fmaxf(a2, 0.f);
    __syncthreads();
    h[wave][lane] = a2;
    __syncthreads();

    // layer 3: 64 -> 32 (no act).  Both half-waves compute the same feats.
    const int o = lane & 31;
    float f = b3[o];
#pragma unroll 8
    for (int c = 0; c < 64; ++c)
        f = fmaf(h[wave][c], w3[c * 32 + o], f);
    __syncthreads();
    if (lane < 32) h[wave][lane] = f;
    __syncthreads();

    // u (lanes 0..31) / v (lanes 32..63): feats @ sm_w1 halves
    const float* sw = smw1 + ((lane < 32) ? 0 : 32 * 32);
    float uv = (lane < 32) ? smb1[o] : 0.f;
#pragma unroll 8
    for (int c = 0; c < 32; ++c)
        uv = fmaf(h[wave][c], sw[c * 32 + o], uv);

    const int bb = urow / NN;
    const int nn = urow - bb * NN;
    // interleaved store: feature o -> (q = o>>2, c = o&3)
    float* dst = ((lane < 32) ? U : V)
               + (((size_t)nn * 8 + (o >> 2)) * 32 + bb) * 4 + (o & 3);
    *dst = uv;
}

// ---------------------------------------------------------------------------
// Kernel 2: similarity MLP over all pairs.  Thread = (b, p); 8 pairs/block.
// U/V reads are fully coalesced: lane b reads float4 at [(i*8+q)*32+b].
// Writes sT[p*32 + b] = tanh(...) (s transposed for the big GEMM).
// ---------------------------------------------------------------------------
__device__ __forceinline__ int cfun(int i) {           // pairs before row i
    return i * NN - (i * (i + 1)) / 2;
}

__global__ __launch_bounds__(256, 1) void sim_kernel(
    const float* __restrict__ U, const float* __restrict__ V,
    const float* __restrict__ w2, const float* __restrict__ b2,
    const float* __restrict__ w3, const float* __restrict__ b3,
    const float* __restrict__ w4, const float* __restrict__ b4,
    float* __restrict__ sT)
{
    const int t = threadIdx.x;
    const int b = t & 31;
    const int p = blockIdx.x * 8 + (t >> 5);
    if (p >= NP) return;

    // invert triangular index: largest i with cfun(i) <= p
    int i = (int)((527.0f - sqrtf(277729.0f - 8.0f * (float)p)) * 0.5f);
    i = max(0, min(NN - 2, i));
    while (i < NN - 2 && cfun(i + 1) <= p) ++i;
    while (i > 0 && cfun(i) > p) --i;
    const int j = i + 1 + (p - cfun(i));

    const float4* u4 = (const float4*)U + (size_t)i * 256 + b;   // +q*32 steps
    const float4* v4 = (const float4*)V + (size_t)j * 256 + b;

    float h2[16];
#pragma unroll
    for (int o = 0; o < 16; ++o) h2[o] = b2[o];

#pragma unroll
    for (int q = 0; q < 8; ++q) {
        float4 uu = u4[q * 32], vv = v4[q * 32];
        float h1c[4];
        h1c[0] = fmaxf(uu.x + vv.x, 0.f);
        h1c[1] = fmaxf(uu.y + vv.y, 0.f);
        h1c[2] = fmaxf(uu.z + vv.z, 0.f);
        h1c[3] = fmaxf(uu.w + vv.w, 0.f);
#pragma unroll
        for (int c = 0; c < 4; ++c)
#pragma unroll
            for (int o = 0; o < 16; ++o)
                h2[o] = fmaf(h1c[c], w2[(q * 4 + c) * 16 + o], h2[o]);
    }
#pragma unroll
    for (int o = 0; o < 16; ++o) h2[o] = fmaxf(h2[o], 0.f);

    float h3[8];
#pragma unroll
    for (int o = 0; o < 8; ++o) h3[o] = b3[o];
#pragma unroll
    for (int c = 0; c < 16; ++c)
#pragma unroll
        for (int o = 0; o < 8; ++o)
            h3[o] = fmaf(h2[c], w3[c * 8 + o], h3[o]);
#pragma unroll
    for (int o = 0; o < 8; ++o) h3[o] = fmaxf(h3[o], 0.f);

    float z = b4[0];
#pragma unroll
    for (int c = 0; c < 8; ++c) z = fmaf(h3[c], w4[c], z);

    sT[(size_t)p * 32 + b] = tanhf(z);
}

// ---------------------------------------------------------------------------
// Kernel 3/5: split-K GEMM  C[m,n] = sum_k aT[k,m] * w[k,n]   (m = 0..31)
// EXPLICIT register software pipeline:
//   - w stream: UF=4 float2 loads always in flight (rotating wreg/wnxt)
//   - aT row:   read 1 k ahead from LDS into areg (ds latency hidden by FMAs)
// Thread = 2 columns (float2 w loads), block = 512 columns, 68KB LDS K-slice
// -> 2 blocks/CU, 8 waves/CU.  vmcnt queue carries ONLY the HBM w stream.
// ---------------------------------------------------------------------------
#define GK_UF  4
#define TILE_K 543           // rows staged per LDS tile (+1 pad row allocated)

__global__ __launch_bounds__(256, 2) void gemm_bigk(
    const float* __restrict__ aT, const float* __restrict__ w,
    float* __restrict__ partial, int K, int N, int chunk)
{
    __shared__ float sa[(TILE_K + 1) * 32];          // 69632 B
    const int tid = threadIdx.x;
    const int n   = blockIdx.x * 512 + tid * 2;
    const bool nok = (n < N);                        // wave-uniform mask
    const int k0s = blockIdx.y * chunk;
    const int k1s = min(k0s + chunk, K);

    float2 acc[32];
#pragma unroll
    for (int m = 0; m < 32; ++m) acc[m] = make_float2(0.f, 0.f);

    for (int kt = k0s; kt < k1s; kt += TILE_K) {
        const int klen = min(TILE_K, k1s - kt);      // >= 8 for all our shapes
        __syncthreads();
        {   // stage aT tile, coalesced float4 (sT is L2/L3-resident)
            const float4* src = (const float4*)(aT + (size_t)kt * 32);
            float4* dst = (float4*)sa;
            for (int i = tid; i < klen * 8; i += 256) dst[i] = src[i];
        }
        __syncthreads();

        const float* wp = nok ? (w + (size_t)kt * N + n) : w;

        // ---- pipeline prologue: 4 w-loads in flight + aT row 0 in regs ----
        float2 wreg[GK_UF];
#pragma unroll
        for (int u = 0; u < GK_UF; ++u)
            wreg[u] = *(const float2*)(wp + (size_t)u * N);
        float4 areg[8];
#pragma unroll
        for (int mq = 0; mq < 8; ++mq)
            areg[mq] = ((const float4*)sa)[mq];

        int k = 0;
        while (k + 2 * GK_UF <= klen) {
            // issue the NEXT 4 w-loads before consuming the current group
            float2 wnxt[GK_UF];
#pragma unroll
            for (int u = 0; u < GK_UF; ++u)
                wnxt[u] = *(const float2*)(wp + (size_t)(k + GK_UF + u) * N);
#pragma unroll
            for (int u = 0; u < GK_UF; ++u) {
                // prefetch aT row k+u+1 from LDS (lands during the 64 FMAs)
                const float4* a4n = (const float4*)(sa + (k + u + 1) * 32);
                float4 anext[8];
#pragma unroll
                for (int mq = 0; mq < 8; ++mq) anext[mq] = a4n[mq];
                const float2 wv = wreg[u];
#pragma unroll
                for (int mq = 0; mq < 8; ++mq) {
                    acc[mq*4+0].x = fmaf(areg[mq].x, wv.x, acc[mq*4+0].x);
                    acc[mq*4+0].y = fmaf(areg[mq].x, wv.y, acc[mq*4+0].y);
                    acc[mq*4+1].x = fmaf(areg[mq].y, wv.x, acc[mq*4+1].x);
                    acc[mq*4+1].y = fmaf(areg[mq].y, wv.y, acc[mq*4+1].y);
                    acc[mq*4+2].x = fmaf(areg[mq].z, wv.x, acc[mq*4+2].x);
                    acc[mq*4+2].y = fmaf(areg[mq].z, wv.y, acc[mq*4+2].y);
                    acc[mq*4+3].x = fmaf(areg[mq].w, wv.x, acc[mq*4+3].x);
                    acc[mq*4+3].y = fmaf(areg[mq].w, wv.y, acc[mq*4+3].y);
                }
#pragma unroll
                for (int mq = 0; mq < 8; ++mq) areg[mq] = anext[mq];
            }
#pragma unroll
            for (int u = 0; u < GK_UF; ++u) wreg[u] = wnxt[u];
            k += GK_UF;
        }
        // ---- drain: wreg group, then <=3 direct iterations ----
#pragma unroll
        for (int u = 0; u < GK_UF; ++u) {
            const float4* a4n = (const float4*)(sa + (k + u + 1) * 32);
            float4 anext[8];
#pragma unroll
            for (int mq = 0; mq < 8; ++mq) anext[mq] = a4n[mq];
            const float2 wv = wreg[u];
#pragma unroll
            for (int mq = 0; mq < 8; ++mq) {
                acc[mq*4+0].x = fmaf(areg[mq].x, wv.x, acc[mq*4+0].x);
                acc[mq*4+0].y = fmaf(areg[mq].x, wv.y, acc[mq*4+0].y);
                acc[mq*4+1].x = fmaf(areg[mq].y, wv.x, acc[mq*4+1].x);
                acc[mq*4+1].y = fmaf(areg[mq].y, wv.y, acc[mq*4+1].y);
                acc[mq*4+2].x = fmaf(areg[mq].z, wv.x, acc[mq*4+2].x);
                acc[mq*4+2].y = fmaf(areg[mq].z, wv.y, acc[mq*4+2].y);
                acc[mq*4+3].x = fmaf(areg[mq].w, wv.x, acc[mq*4+3].x);
                acc[mq*4+3].y = fmaf(areg[mq].w, wv.y, acc[mq*4+3].y);
            }
#pragma unroll
            for (int mq = 0; mq < 8; ++mq) areg[mq] = anext[mq];
        }
        for (int kk = k + GK_UF; kk < klen; ++kk) {
            const float2 wv = *(const float2*)(wp + (size_t)kk * N);
            const float4* a4n = (const float4*)(sa + (kk + 1) * 32);
            float4 anext[8];
#pragma unroll
            for (int mq = 0; mq < 8; ++mq) anext[mq] = a4n[mq];
#pragma unroll
            for (int mq = 0; mq < 8; ++mq) {
                acc[mq*4+0].x = fmaf(areg[mq].x, wv.x, acc[mq*4+0].x);
                acc[mq*4+0].y = fmaf(areg[mq].x, wv.y, acc[mq*4+0].y);
                acc[mq*4+1].x = fmaf(areg[mq].y, wv.x, acc[mq*4+1].x);
                acc[mq*4+1].y = fmaf(areg[mq].y, wv.y, acc[mq*4+1].y);
                acc[mq*4+2].x = fmaf(areg[mq].z, wv.x, acc[mq*4+2].x);
                acc[mq*4+2].y = fmaf(areg[mq].z, wv.y, acc[mq*4+2].y);
                acc[mq*4+3].x = fmaf(areg[mq].w, wv.x, acc[mq*4+3].x);
                acc[mq*4+3].y = fmaf(areg[mq].w, wv.y, acc[mq*4+3].y);
            }
#pragma unroll
            for (int mq = 0; mq < 8; ++mq) areg[mq] = anext[mq];
        }
    }

    if (nok) {
        // columns n (x) and n+1 (y); layout partial[(ns*N + n)*32 + m]
        float4* po4 = (float4*)(partial + ((size_t)blockIdx.y * N + n) * 32);
#pragma unroll
        for (int mq = 0; mq < 8; ++mq)
            po4[mq] = make_float4(acc[mq*4+0].x, acc[mq*4+1].x,
                                  acc[mq*4+2].x, acc[mq*4+3].x);
#pragma unroll
        for (int mq = 0; mq < 8; ++mq)
            po4[8 + mq] = make_float4(acc[mq*4+0].y, acc[mq*4+1].y,
                                      acc[mq*4+2].y, acc[mq*4+3].y);
    }
}

// ---------------------------------------------------------------------------
// Kernel 4/6: reduce split-K partials + bias + activation.
// out[n*32+b] layout == aT layout for the next GEMM.  mode 0=rrelu, 1=relu
// ---------------------------------------------------------------------------
__global__ __launch_bounds__(256) void reduce_act(
    const float* __restrict__ partial, const float* __restrict__ bias,
    float* __restrict__ out, int NT, int ns_count, int mode)
{
    const int idx = blockIdx.x * 256 + threadIdx.x;   // < NT = N*32
    const int n = idx >> 5;
    float s = bias[n];
#pragma unroll 4
    for (int ns = 0; ns < ns_count; ++ns)
        s += partial[(size_t)ns * NT + idx];
    out[idx] = (mode == 0) ? ((s >= 0.f) ? s : s * RRELU_SLOPE) : fmaxf(s, 0.f);
}

// ---------------------------------------------------------------------------
// Kernel 7: layer3 (256 -> 64, relu).  8 blocks; thread = (b, o).
// c3T[o*32+b]
// ---------------------------------------------------------------------------
__global__ __launch_bounds__(256) void layer3_kernel(
    const float* __restrict__ c2T, const float* __restrict__ w3,
    const float* __restrict__ b3, float* __restrict__ c3T)
{
    const int t = threadIdx.x;
    const int b = t & 31;
    const int o = blockIdx.x * 8 + (t >> 5);
    float acc = b3[o];
#pragma unroll 8
    for (int k = 0; k < 256; ++k)
        acc = fmaf(c2T[k * 32 + b], w3[k * 64 + o], acc);
    c3T[o * 32 + b] = fmaxf(acc, 0.f);
}

// ---------------------------------------------------------------------------
// Kernel 8: layer4 (64 -> 3) + log_softmax.  Single small block.
// ---------------------------------------------------------------------------
__global__ __launch_bounds__(128) void final_kernel(
    const float* __restrict__ c3T, const float* __restrict__ w4,
    const float* __restrict__ b4, float* __restrict__ out)
{
    __shared__ float c4s[96];
    __shared__ float lse[32];
    const int t = threadIdx.x;
    if (t < 96) {
        const int b = t / 3, j = t - b * 3;
        float acc = b4[j];
#pragma unroll
        for (int c = 0; c < 64; ++c)
            acc = fmaf(c3T[c * 32 + b], w4[c * 3 + j], acc);
        c4s[t] = acc;
    }
    __syncthreads();
    if (t < 32) {
        const float a0 = c4s[t * 3], a1 = c4s[t * 3 + 1], a2 = c4s[t * 3 + 2];
        const float m = fmaxf(a0, fmaxf(a1, a2));
        lse[t] = m + logf(expf(a0 - m) + expf(a1 - m) + expf(a2 - m));
    }
    __syncthreads();
    if (t < 96) out[t] = c4s[t] - lse[t / 3];
}

// ---------------------------------------------------------------------------
extern "C" void kernel_launch(void* const* d_in, const int* in_sizes, int n_in,
                              void* d_out, int out_size, void* d_ws, size_t ws_size,
                              hipStream_t stream)
{
    const float* x     = (const float*)d_in[0];
    const float* fe_w1 = (const float*)d_in[1];
    const float* fe_b1 = (const float*)d_in[2];
    const float* fe_w2 = (const float*)d_in[3];
    const float* fe_b2 = (const float*)d_in[4];
    const float* fe_w3 = (const float*)d_in[5];
    const float* fe_b3 = (const float*)d_in[6];
    const float* sm_w1 = (const float*)d_in[7];
    const float* sm_b1 = (const float*)d_in[8];
    const float* sm_w2 = (const float*)d_in[9];
    const float* sm_b2 = (const float*)d_in[10];
    const float* sm_w3 = (const float*)d_in[11];
    const float* sm_b3 = (const float*)d_in[12];
    const float* sm_w4 = (const float*)d_in[13];
    const float* sm_b4 = (const float*)d_in[14];
    const float* cl_w1 = (const float*)d_in[15];
    const float* cl_b1 = (const float*)d_in[16];
    const float* cl_w2 = (const float*)d_in[17];
    const float* cl_b2 = (const float*)d_in[18];
    const float* cl_w3 = (const float*)d_in[19];
    const float* cl_b3 = (const float*)d_in[20];
    const float* cl_w4 = (const float*)d_in[21];
    const float* cl_b4 = (const float*)d_in[22];

    // split-K factor for the big GEMM: 64 slices needs ~41MB workspace;
    // fall back to 32 slices (23.9MB, proven to fit) if ws is small.
    const int NS1 = (ws_size >= 41000000ull) ? 64 : 32;
    const int CHUNK1 = (NP + NS1 - 1) / NS1;          // 543 or 1085

    float* ws  = (float*)d_ws;
    float* U   = ws;                          // 270336
    float* V   = U   + 270336;                // 270336
    float* sT  = V   + 270336;                // 34716*32 = 1110912
    float* p1  = sT  + 1110912;               // NS1*4096*32
    float* c1T = p1  + (size_t)NS1 * 131072;  // 131072
    float* p2  = p1;                          // alias: p1 dead before layer2 GEMM
    float* c2T = c1T + 131072;                // 8192
    float* c3T = c2T + 8192;                  // 2048

    // 1) feature extractor + u/v  (8448 rows, 4 waves/block)
    hipLaunchKernelGGL(fe_uv_kernel, dim3(2112), dim3(256), 0, stream,
                       x, fe_w1, fe_b1, fe_w2, fe_b2, fe_w3, fe_b3,
                       sm_w1, sm_b1, U, V);
    // 2) pair similarity MLP -> sT[p][b]
    hipLaunchKernelGGL(sim_kernel, dim3((NP + 7) / 8), dim3(256), 0, stream,
                       U, V, sm_w2, sm_b2, sm_w3, sm_b3, sm_w4, sm_b4, sT);
    // 3) big GEMM: s[32,P] @ cl_w1[P,4096]  (split-K NS1, pipelined)
    hipLaunchKernelGGL(gemm_bigk, dim3(8, NS1), dim3(256), 0, stream,
                       sT, cl_w1, p1, NP, 4096, CHUNK1);
    // 4) reduce + bias + rrelu -> c1T[4096][32]
    hipLaunchKernelGGL(reduce_act, dim3(512), dim3(256), 0, stream,
                       p1, cl_b1, c1T, 4096 * 32, NS1, 0);
    // 5) layer2 GEMM: c1[32,4096] @ cl_w2[4096,256]  (split-K 128)
    hipLaunchKernelGGL(gemm_bigk, dim3(1, 128), dim3(256), 0, stream,
                       c1T, cl_w2, p2, 4096, 256, 32);
    // 6) reduce + bias + relu -> c2T[256][32]
    hipLaunchKernelGGL(reduce_act, dim3(32), dim3(256), 0, stream,
                       p2, cl_b2, c2T, 256 * 32, 128, 1);
    // 7) layer3: 256 -> 64, relu -> c3T[64][32]
    hipLaunchKernelGGL(layer3_kernel, dim3(8), dim3(256), 0, stream,
                       c2T, cl_w3, cl_b3, c3T);
    // 8) layer4 + log_softmax -> out[32,3]
    hipLaunchKernelGGL(final_kernel, dim3(1), dim3(128), 0, stream,
                       c3T, cl_w4, cl_b4, (float*)d_out);
}